// Round 1
// baseline (228.746 us; speedup 1.0000x reference)
//
#include <hip/hip_runtime.h>

#define NN 50000
#define EE 600000
#define CC 128
#define HH 8

typedef unsigned int u32;
typedef unsigned short u16;

__device__ __forceinline__ float b2f(u32 u) {
  return __uint_as_float(u << 16);
}
__device__ __forceinline__ u16 f2b(float f) {
  u32 x = __float_as_uint(f);
  u32 r = (x + 0x7fffu + ((x >> 16) & 1u)) >> 16;
  return (u16)r;
}

// workspace layout in 4-byte words
enum : int {
  OFF_FLAG = 0,
  OFF_SRC  = 64,
  OFF_TRG  = OFF_SRC + EE,
  OFF_CNT  = OFF_TRG + EE,
  OFF_OFFS = OFF_CNT + NN,
  OFF_CUR  = OFF_OFFS + NN + 64,
  OFF_BSUM = OFF_CUR + NN,
  OFF_WT   = OFF_BSUM + 256,
  OFF_SL   = OFF_WT + CC * CC,
  OFF_SR   = OFF_SL + NN * HH,
  OFF_SSRC = OFF_SR + NN * HH,
  OFF_EMB  = OFF_SSRC + EE,          // bf16 emb: NN*64 u32 words
  WS_WORDS = OFF_EMB + NN * 64
};

// ---- edge dtype sniffing: int32 vs int64 ----------------------------------
__global__ __launch_bounds__(256) void k_detect(const int* __restrict__ ei, int* __restrict__ flag) {
  __shared__ int any;
  if (threadIdx.x == 0) any = 0;
  __syncthreads();
  int nz = 0;
  for (int k = threadIdx.x; k < 1024; k += 256) nz |= (ei[2 * k + 1] != 0) ? 1 : 0;
  if (nz) any = 1;          // benign race
  __syncthreads();
  if (threadIdx.x == 0) flag[0] = any;   // 1 => int32 layout, 0 => int64 layout
}

__global__ __launch_bounds__(256) void k_norm(const int* __restrict__ ei, const int* __restrict__ flag,
                                              int* __restrict__ srcN, int* __restrict__ trgN) {
  int e = blockIdx.x * 256 + threadIdx.x;
  if (e >= EE) return;
  if (flag[0]) {
    srcN[e] = ei[e];
    trgN[e] = ei[EE + e];
  } else {
    srcN[e] = ei[2 * e];
    trgN[e] = ei[2 * EE + 2 * e];
  }
}

// ---- W transpose (for coalesced LDS staging in GEMM) ----------------------
__global__ __launch_bounds__(256) void k_transW(const float* __restrict__ W, float* __restrict__ Wt) {
  int idx = blockIdx.x * 256 + threadIdx.x;
  if (idx >= CC * CC) return;
  int i = idx >> 7, o = idx & 127;
  Wt[idx] = W[o * CC + i];             // Wt[i][o] = W[o][i]
}

// ---- GEMM: emb[n][o] = sum_c X[n][c] * W[o][c], stored bf16 ---------------
__global__ __launch_bounds__(256) void k_gemm(const float* __restrict__ X,
                                              const float* __restrict__ Wt,
                                              u32* __restrict__ emb) {
  __shared__ float Ws[CC][132];
  __shared__ float Xs[64][132];
  const int tid = threadIdx.x;
  const int n0 = blockIdx.x * 64;
  for (int idx = tid; idx < CC * CC / 4; idx += 256) {
    int i = idx >> 5, q = idx & 31;
    float4 v = ((const float4*)Wt)[idx];
    *(float4*)&Ws[i][q * 4] = v;
  }
  for (int idx = tid; idx < 64 * CC / 4; idx += 256) {
    int r = idx >> 5, q = idx & 31;
    int n = n0 + r;
    float4 v = make_float4(0.f, 0.f, 0.f, 0.f);
    if (n < NN) v = ((const float4*)X)[n * (CC / 4) + q];
    *(float4*)&Xs[r][q * 4] = v;
  }
  __syncthreads();
  const int og = tid & 15, ng = tid >> 4;
  float acc[4][8];
#pragma unroll
  for (int i = 0; i < 4; ++i)
#pragma unroll
    for (int j = 0; j < 8; ++j) acc[i][j] = 0.f;
#pragma unroll 4
  for (int c = 0; c < CC; ++c) {
    float4 wa = *(const float4*)&Ws[c][og * 8];
    float4 wb = *(const float4*)&Ws[c][og * 8 + 4];
    float w[8] = {wa.x, wa.y, wa.z, wa.w, wb.x, wb.y, wb.z, wb.w};
    float x[4];
#pragma unroll
    for (int i = 0; i < 4; ++i) x[i] = Xs[ng * 4 + i][c];
#pragma unroll
    for (int i = 0; i < 4; ++i)
#pragma unroll
      for (int j = 0; j < 8; ++j) acc[i][j] = fmaf(x[i], w[j], acc[i][j]);
  }
#pragma unroll
  for (int i = 0; i < 4; ++i) {
    int n = n0 + ng * 4 + i;
    if (n < NN) {
      u32 p[4];
#pragma unroll
      for (int j = 0; j < 4; ++j)
        p[j] = (u32)f2b(acc[i][2 * j]) | ((u32)f2b(acc[i][2 * j + 1]) << 16);
      *((uint4*)(emb + n * 64 + og * 4)) = make_uint4(p[0], p[1], p[2], p[3]);
    }
  }
}

// ---- per-node head scores -------------------------------------------------
__global__ __launch_bounds__(256) void k_scores(const u32* __restrict__ emb,
                                                const float* __restrict__ al, const float* __restrict__ ar,
                                                float* __restrict__ sl, float* __restrict__ sr) {
  int n = blockIdx.x * 256 + threadIdx.x;
  if (n >= NN) return;
  float accl[HH], accr[HH];
#pragma unroll
  for (int h = 0; h < HH; ++h) { accl[h] = 0.f; accr[h] = 0.f; }
#pragma unroll
  for (int q = 0; q < 16; ++q) {            // 8 bf16 per uint4
    uint4 v = ((const uint4*)(emb + n * 64))[q];
    const int h = q >> 1;
    const int cb = (q & 1) * 8;
    float f[8] = {b2f(v.x & 0xffffu), b2f(v.x >> 16), b2f(v.y & 0xffffu), b2f(v.y >> 16),
                  b2f(v.z & 0xffffu), b2f(v.z >> 16), b2f(v.w & 0xffffu), b2f(v.w >> 16)};
#pragma unroll
    for (int j = 0; j < 8; ++j) {
      accl[h] = fmaf(f[j], al[(cb + j) * HH + h], accl[h]);
      accr[h] = fmaf(f[j], ar[(cb + j) * HH + h], accr[h]);
    }
  }
#pragma unroll
  for (int h = 0; h < HH; ++h) { sl[n * HH + h] = accl[h]; sr[n * HH + h] = accr[h]; }
}

// ---- CSR build: histogram, scan (3 kernels), scatter ----------------------
__global__ __launch_bounds__(256) void k_hist(const int* __restrict__ trg, int* __restrict__ cnt) {
  int e = blockIdx.x * 256 + threadIdx.x;
  if (e < EE) atomicAdd(&cnt[trg[e]], 1);
}

__global__ __launch_bounds__(256) void k_scanA(const int* __restrict__ cnt, int* __restrict__ offs,
                                               int* __restrict__ bsum) {
  __shared__ int tmp[256];
  const int t = threadIdx.x;
  const int i = blockIdx.x * 256 + t;
  int v = (i < NN) ? cnt[i] : 0;
  tmp[t] = v;
  __syncthreads();
#pragma unroll
  for (int d = 1; d < 256; d <<= 1) {
    int x = (t >= d) ? tmp[t - d] : 0;
    __syncthreads();
    tmp[t] += x;
    __syncthreads();
  }
  if (i < NN) offs[i] = tmp[t] - v;      // block-local exclusive
  if (t == 255) bsum[blockIdx.x] = tmp[255];
}

__global__ __launch_bounds__(256) void k_scanB(int* __restrict__ bsum, int nb) {
  __shared__ int tmp[256];
  const int t = threadIdx.x;
  int v = (t < nb) ? bsum[t] : 0;
  tmp[t] = v;
  __syncthreads();
#pragma unroll
  for (int d = 1; d < 256; d <<= 1) {
    int x = (t >= d) ? tmp[t - d] : 0;
    __syncthreads();
    tmp[t] += x;
    __syncthreads();
  }
  if (t < nb) bsum[t] = tmp[t] - v;      // exclusive
}

__global__ __launch_bounds__(256) void k_scanC(const int* __restrict__ bsum, int* __restrict__ offs,
                                               int* __restrict__ cur) {
  const int i = blockIdx.x * 256 + threadIdx.x;
  if (i < NN) {
    int o = offs[i] + bsum[blockIdx.x];
    offs[i] = o;
    cur[i] = o;
  }
  if (i == 0) offs[NN] = EE;
}

__global__ __launch_bounds__(256) void k_scatter(const int* __restrict__ srcN, const int* __restrict__ trgN,
                                                 int* __restrict__ cur, int* __restrict__ ssrc) {
  int e = blockIdx.x * 256 + threadIdx.x;
  if (e >= EE) return;
  int t = trgN[e];
  int pos = atomicAdd(&cur[t], 1);
  ssrc[pos] = srcN[e];
}

// ---- target-centric aggregation: one wave per node, no float atomics ------
__global__ __launch_bounds__(256) void k_agg(const u32* __restrict__ emb,
                                             const float* __restrict__ sl, const float* __restrict__ sr,
                                             const int* __restrict__ offs, const int* __restrict__ ssrc,
                                             const float* __restrict__ bias, float* __restrict__ out) {
  const int gw = (blockIdx.x * 256 + threadIdx.x) >> 6;
  const int lane = threadIdx.x & 63;
  if (gw >= NN) return;
  const int t = gw;
  const int e0 = offs[t], e1 = offs[t + 1];
  const int ne = e1 - e0;
  const int h = lane & 7;
  const float srh = sr[t * HH + h];
  float den = 0.f;
  for (int b = lane >> 3; b < ne; b += 8) {
    int s = ssrc[e0 + b];
    float v = sl[s * HH + h] + srh;
    v = (v > 0.f) ? v : 0.2f * v;
    den += __expf(v);
  }
  den += __shfl_xor(den, 8);
  den += __shfl_xor(den, 16);
  den += __shfl_xor(den, 32);
  den += 1e-16f;                       // lane l now holds denom(+eps) for head l&7
  const int h2 = lane >> 3;            // head owning channels (2*lane, 2*lane+1)
  const float den2 = __shfl(den, h2);
  const float sr2 = sr[t * HH + h2];
  float ax = 0.f, ay = 0.f;
  for (int e = 0; e < ne; ++e) {
    int s = ssrc[e0 + e];
    float v = sl[s * HH + h2] + sr2;
    v = (v > 0.f) ? v : 0.2f * v;
    float w = __expf(v) / den2;
    u32 p = emb[s * 64 + lane];
    ax = fmaf(w, b2f(p & 0xffffu), ax);
    ay = fmaf(w, b2f(p >> 16), ay);
  }
  float2 bv = ((const float2*)bias)[lane];
  ((float2*)out)[t * 64 + lane] = make_float2(ax + bv.x, ay + bv.y);
}

extern "C" void kernel_launch(void* const* d_in, const int* in_sizes, int n_in,
                              void* d_out, int out_size, void* d_ws, size_t ws_size,
                              hipStream_t stream) {
  const float* X  = (const float*)d_in[0];
  const int*   EI = (const int*)d_in[1];
  const float* W  = (const float*)d_in[2];
  const float* AL = (const float*)d_in[3];
  const float* AR = (const float*)d_in[4];
  const float* B  = (const float*)d_in[5];
  float* out = (float*)d_out;
  u32* ws = (u32*)d_ws;

  int*   flag = (int*)(ws + OFF_FLAG);
  int*   srcN = (int*)(ws + OFF_SRC);
  int*   trgN = (int*)(ws + OFF_TRG);
  int*   cnt  = (int*)(ws + OFF_CNT);
  int*   offs = (int*)(ws + OFF_OFFS);
  int*   cur  = (int*)(ws + OFF_CUR);
  int*   bsum = (int*)(ws + OFF_BSUM);
  float* Wt   = (float*)(ws + OFF_WT);
  float* sl   = (float*)(ws + OFF_SL);
  float* sr   = (float*)(ws + OFF_SR);
  int*   ssrc = (int*)(ws + OFF_SSRC);
  u32*   emb  = (u32*)(ws + OFF_EMB);

  const int nbN = (NN + 255) / 256;     // 196
  const int nbE = (EE + 255) / 256;     // 2344

  hipMemsetAsync(cnt, 0, NN * sizeof(int), stream);
  k_detect<<<1, 256, 0, stream>>>(EI, flag);
  k_norm<<<nbE, 256, 0, stream>>>(EI, flag, srcN, trgN);
  k_transW<<<(CC * CC + 255) / 256, 256, 0, stream>>>(W, Wt);
  k_gemm<<<(NN + 63) / 64, 256, 0, stream>>>(X, Wt, emb);
  k_scores<<<nbN, 256, 0, stream>>>(emb, AL, AR, sl, sr);
  k_hist<<<nbE, 256, 0, stream>>>(trgN, cnt);
  k_scanA<<<nbN, 256, 0, stream>>>(cnt, offs, bsum);
  k_scanB<<<1, 256, 0, stream>>>(bsum, nbN);
  k_scanC<<<nbN, 256, 0, stream>>>(bsum, offs, cur);
  k_scatter<<<nbE, 256, 0, stream>>>(srcN, trgN, cur, ssrc);
  k_agg<<<(NN * 64) / 256, 256, 0, stream>>>(emb, sl, sr, offs, ssrc, B, out);
}

// Round 2
// 215.680 us; speedup vs baseline: 1.0606x; 1.0606x over previous
//
#include <hip/hip_runtime.h>

#define NN 50000
#define EE 600000
#define CC 128
#define HH 8

typedef unsigned int u32;
typedef unsigned short u16;

__device__ __forceinline__ float b2f(u32 u) {
  return __uint_as_float(u << 16);
}
__device__ __forceinline__ u16 f2b(float f) {
  u32 x = __float_as_uint(f);
  u32 r = (x + 0x7fffu + ((x >> 16) & 1u)) >> 16;
  return (u16)r;
}

// workspace layout in 4-byte words
enum : int {
  OFF_FLAG = 0,
  OFF_CNT  = 64,
  OFF_OFFS = OFF_CNT + NN,
  OFF_CUR  = OFF_OFFS + NN + 64,
  OFF_BSUM = OFF_CUR + NN,
  OFF_SL   = OFF_BSUM + 256,
  OFF_SR   = OFF_SL + NN * HH,
  OFF_SSRC = OFF_SR + NN * HH,
  OFF_EMB  = OFF_SSRC + EE,          // bf16 emb: NN*64 u32 words
  WS_WORDS = OFF_EMB + NN * 64
};

// ---- edge dtype sniffing: int32 vs int64 ----------------------------------
__global__ __launch_bounds__(256) void k_detect(const int* __restrict__ ei, int* __restrict__ flag) {
  __shared__ int any;
  if (threadIdx.x == 0) any = 0;
  __syncthreads();
  int nz = 0;
  for (int k = threadIdx.x; k < 1024; k += 256) nz |= (ei[2 * k + 1] != 0) ? 1 : 0;
  if (nz) any = 1;          // benign race
  __syncthreads();
  if (threadIdx.x == 0) flag[0] = any;   // 1 => int32 layout, 0 => int64 layout
}

// ---- GEMM + fused scores: emb[n][o] = X[n][:]·W[o][:], bf16 stored --------
__global__ __launch_bounds__(256) void k_gemm(const float* __restrict__ X,
                                              const float* __restrict__ W,
                                              const float* __restrict__ al,
                                              const float* __restrict__ ar,
                                              u32* __restrict__ emb,
                                              float* __restrict__ sl, float* __restrict__ sr) {
  __shared__ float Ws[CC][132];
  __shared__ float Xs[64][132];
  __shared__ float sls[64][HH];
  __shared__ float srs[64][HH];
  const int tid = threadIdx.x;
  const int n0 = blockIdx.x * 64;
  for (int i = tid; i < 64 * HH; i += 256) { ((float*)sls)[i] = 0.f; ((float*)srs)[i] = 0.f; }
  // stage W transposed: Ws[c][o] = W[o][c]  (coalesced global read)
  for (int idx = tid; idx < CC * CC; idx += 256) {
    int o = idx >> 7, c = idx & 127;
    Ws[c][o] = W[idx];
  }
  // stage X tile
  for (int idx = tid; idx < 64 * CC / 4; idx += 256) {
    int r = idx >> 5, q = idx & 31;
    int n = n0 + r;
    float4 v = make_float4(0.f, 0.f, 0.f, 0.f);
    if (n < NN) v = ((const float4*)X)[n * (CC / 4) + q];
    *(float4*)&Xs[r][q * 4] = v;
  }
  __syncthreads();
  const int og = tid & 15, ng = tid >> 4;
  float acc[4][8];
#pragma unroll
  for (int i = 0; i < 4; ++i)
#pragma unroll
    for (int j = 0; j < 8; ++j) acc[i][j] = 0.f;
#pragma unroll 4
  for (int c = 0; c < CC; ++c) {
    float4 wa = *(const float4*)&Ws[c][og * 8];
    float4 wb = *(const float4*)&Ws[c][og * 8 + 4];
    float w[8] = {wa.x, wa.y, wa.z, wa.w, wb.x, wb.y, wb.z, wb.w};
    float x[4];
#pragma unroll
    for (int i = 0; i < 4; ++i) x[i] = Xs[ng * 4 + i][c];
#pragma unroll
    for (int i = 0; i < 4; ++i)
#pragma unroll
      for (int j = 0; j < 8; ++j) acc[i][j] = fmaf(x[i], w[j], acc[i][j]);
  }
  // emb store (bf16 packed)
#pragma unroll
  for (int i = 0; i < 4; ++i) {
    int n = n0 + ng * 4 + i;
    if (n < NN) {
      u32 p[4];
#pragma unroll
      for (int j = 0; j < 4; ++j)
        p[j] = (u32)f2b(acc[i][2 * j]) | ((u32)f2b(acc[i][2 * j + 1]) << 16);
      *((uint4*)(emb + n * 64 + og * 4)) = make_uint4(p[0], p[1], p[2], p[3]);
    }
  }
  // fused per-node head scores: channels og*8..og*8+7 all belong to head og>>1
  const int hh = og >> 1;
  const int cwb = (og & 1) * 8;      // channel-within-head base
  float av[8], bv[8];
#pragma unroll
  for (int j = 0; j < 8; ++j) {
    av[j] = al[(cwb + j) * HH + hh];
    bv[j] = ar[(cwb + j) * HH + hh];
  }
#pragma unroll
  for (int i = 0; i < 4; ++i) {
    float pl = 0.f, pr = 0.f;
#pragma unroll
    for (int j = 0; j < 8; ++j) {
      pl = fmaf(acc[i][j], av[j], pl);
      pr = fmaf(acc[i][j], bv[j], pr);
    }
    atomicAdd(&sls[ng * 4 + i][hh], pl);
    atomicAdd(&srs[ng * 4 + i][hh], pr);
  }
  __syncthreads();
  for (int idx = tid; idx < 64 * HH; idx += 256) {
    int n = n0 + (idx >> 3);
    if (n < NN) {
      sl[n * HH + (idx & 7)] = ((float*)sls)[idx];
      sr[n * HH + (idx & 7)] = ((float*)srs)[idx];
    }
  }
}

// ---- CSR build: histogram (direct from edge_index), scan, scatter ---------
__global__ __launch_bounds__(256) void k_hist(const int* __restrict__ ei, const int* __restrict__ flag,
                                              int* __restrict__ cnt) {
  int e = blockIdx.x * 256 + threadIdx.x;
  if (e >= EE) return;
  int t = flag[0] ? ei[EE + e] : ei[2 * EE + 2 * e];
  atomicAdd(&cnt[t], 1);
}

__global__ __launch_bounds__(256) void k_scanA(const int* __restrict__ cnt, int* __restrict__ offs,
                                               int* __restrict__ bsum) {
  __shared__ int tmp[256];
  const int t = threadIdx.x;
  const int i = blockIdx.x * 256 + t;
  int v = (i < NN) ? cnt[i] : 0;
  tmp[t] = v;
  __syncthreads();
#pragma unroll
  for (int d = 1; d < 256; d <<= 1) {
    int x = (t >= d) ? tmp[t - d] : 0;
    __syncthreads();
    tmp[t] += x;
    __syncthreads();
  }
  if (i < NN) offs[i] = tmp[t] - v;      // block-local exclusive
  if (t == 255) bsum[blockIdx.x] = tmp[255];
}

__global__ __launch_bounds__(256) void k_scanB(int* __restrict__ bsum, int nb) {
  __shared__ int tmp[256];
  const int t = threadIdx.x;
  int v = (t < nb) ? bsum[t] : 0;
  tmp[t] = v;
  __syncthreads();
#pragma unroll
  for (int d = 1; d < 256; d <<= 1) {
    int x = (t >= d) ? tmp[t - d] : 0;
    __syncthreads();
    tmp[t] += x;
    __syncthreads();
  }
  if (t < nb) bsum[t] = tmp[t] - v;      // exclusive
}

__global__ __launch_bounds__(256) void k_scanC(const int* __restrict__ bsum, int* __restrict__ offs,
                                               int* __restrict__ cur) {
  const int i = blockIdx.x * 256 + threadIdx.x;
  if (i < NN) {
    int o = offs[i] + bsum[blockIdx.x];
    offs[i] = o;
    cur[i] = o;
  }
  if (i == 0) offs[NN] = EE;
}

__global__ __launch_bounds__(256) void k_scatter(const int* __restrict__ ei, const int* __restrict__ flag,
                                                 int* __restrict__ cur, int* __restrict__ ssrc) {
  int e = blockIdx.x * 256 + threadIdx.x;
  if (e >= EE) return;
  int t, s;
  if (flag[0]) { s = ei[e]; t = ei[EE + e]; }
  else         { s = ei[2 * e]; t = ei[2 * EE + 2 * e]; }
  int pos = atomicAdd(&cur[t], 1);
  ssrc[pos] = s;
}

// ---- single-pass target-centric aggregation (num and den together) --------
__global__ __launch_bounds__(256) void k_agg(const u32* __restrict__ emb,
                                             const float* __restrict__ sl, const float* __restrict__ sr,
                                             const int* __restrict__ offs, const int* __restrict__ ssrc,
                                             const float* __restrict__ bias, float* __restrict__ out) {
  const int t = (blockIdx.x * 256 + threadIdx.x) >> 6;
  const int lane = threadIdx.x & 63;
  if (t >= NN) return;
  const int e0 = offs[t], e1 = offs[t + 1];
  const int h2 = lane >> 3;            // head owning channels (2*lane, 2*lane+1)
  const float sr2 = sr[t * HH + h2];
  float ax = 0.f, ay = 0.f, den = 0.f;
  for (int e = e0; e < e1; ++e) {
    int s = ssrc[e];
    float v = sl[s * HH + h2] + sr2;
    v = (v > 0.f) ? v : 0.2f * v;
    float w = __expf(v);
    den += w;
    u32 p = emb[s * 64 + lane];
    ax = fmaf(w, b2f(p & 0xffffu), ax);
    ay = fmaf(w, b2f(p >> 16), ay);
  }
  const float inv = 1.f / (den + 1e-16f);
  float2 bv = ((const float2*)bias)[lane];
  ((float2*)out)[t * 64 + lane] = make_float2(fmaf(ax, inv, bv.x), fmaf(ay, inv, bv.y));
}

extern "C" void kernel_launch(void* const* d_in, const int* in_sizes, int n_in,
                              void* d_out, int out_size, void* d_ws, size_t ws_size,
                              hipStream_t stream) {
  const float* X  = (const float*)d_in[0];
  const int*   EI = (const int*)d_in[1];
  const float* W  = (const float*)d_in[2];
  const float* AL = (const float*)d_in[3];
  const float* AR = (const float*)d_in[4];
  const float* B  = (const float*)d_in[5];
  float* out = (float*)d_out;
  u32* ws = (u32*)d_ws;

  int*   flag = (int*)(ws + OFF_FLAG);
  int*   cnt  = (int*)(ws + OFF_CNT);
  int*   offs = (int*)(ws + OFF_OFFS);
  int*   cur  = (int*)(ws + OFF_CUR);
  int*   bsum = (int*)(ws + OFF_BSUM);
  float* sl   = (float*)(ws + OFF_SL);
  float* sr   = (float*)(ws + OFF_SR);
  int*   ssrc = (int*)(ws + OFF_SSRC);
  u32*   emb  = (u32*)(ws + OFF_EMB);

  const int nbN = (NN + 255) / 256;     // 196
  const int nbE = (EE + 255) / 256;     // 2344

  hipMemsetAsync(cnt, 0, NN * sizeof(int), stream);
  k_detect<<<1, 256, 0, stream>>>(EI, flag);
  k_gemm<<<(NN + 63) / 64, 256, 0, stream>>>(X, W, AL, AR, emb, sl, sr);
  k_hist<<<nbE, 256, 0, stream>>>(EI, flag, cnt);
  k_scanA<<<nbN, 256, 0, stream>>>(cnt, offs, bsum);
  k_scanB<<<1, 256, 0, stream>>>(bsum, nbN);
  k_scanC<<<nbN, 256, 0, stream>>>(bsum, offs, cur);
  k_scatter<<<nbE, 256, 0, stream>>>(EI, flag, cur, ssrc);
  k_agg<<<(NN * 64 + 255) / 256, 256, 0, stream>>>(emb, sl, sr, offs, ssrc, B, out);
}

// Round 3
// 146.039 us; speedup vs baseline: 1.5663x; 1.4769x over previous
//
#include <hip/hip_runtime.h>

#define NN 50000
#define EE 600000
#define CC 128
#define HH 8

typedef unsigned int u32;
typedef unsigned short u16;
typedef __attribute__((ext_vector_type(8))) short short8;
typedef __attribute__((ext_vector_type(4))) float f32x4;

__device__ __forceinline__ float b2f(u32 u) {
  return __uint_as_float(u << 16);
}
__device__ __forceinline__ u16 f2b(float f) {
  u32 x = __float_as_uint(f);
  u32 r = (x + 0x7fffu + ((x >> 16) & 1u)) >> 16;
  return (u16)r;
}

// workspace layout in 4-byte words (same as round 2)
enum : int {
  OFF_FLAG = 0,
  OFF_CNT  = 64,
  OFF_OFFS = OFF_CNT + NN,
  OFF_CUR  = OFF_OFFS + NN + 64,
  OFF_BSUM = OFF_CUR + NN,
  OFF_SL   = OFF_BSUM + 256,
  OFF_SR   = OFF_SL + NN * HH,
  OFF_SSRC = OFF_SR + NN * HH,
  OFF_EMB  = OFF_SSRC + EE,          // bf16 emb: NN*64 u32 words
  WS_WORDS = OFF_EMB + NN * 64
};

// ---- edge dtype sniff (block 0) + cnt zeroing (all blocks) ----------------
__global__ __launch_bounds__(256) void k_detect_zero(const int* __restrict__ ei,
                                                     int* __restrict__ flag, int* __restrict__ cnt) {
  int i = blockIdx.x * 256 + threadIdx.x;
  if (i < NN) cnt[i] = 0;
  if (blockIdx.x == 0) {
    __shared__ int any;
    if (threadIdx.x == 0) any = 0;
    __syncthreads();
    int nz = 0;
    for (int k = threadIdx.x; k < 1024; k += 256) nz |= (ei[2 * k + 1] != 0) ? 1 : 0;
    if (nz) any = 1;  // benign race
    __syncthreads();
    if (threadIdx.x == 0) flag[0] = any;  // 1 => int32 layout, 0 => int64 layout
  }
}

// ---- MFMA bf16 GEMM + fused scores ---------------------------------------
// emb[n][o] = sum_c X[n][c] * W[o][c]; block = 64 rows, 4 waves, wave = 16 rows x 128 cols.
#define WS_BASE 0              // bf16 W[128][128], 32 KB, XOR-swizzled
#define XS_BASE 32768          // bf16 X-tile[64][128], 16 KB, XOR-swizzled (reused for out-stage)
__device__ __forceinline__ int swz(int row, int byte_in_row) {
  return ((row * 256 + byte_in_row) ^ ((row & 7) << 4));
}

__global__ __launch_bounds__(256) void k_gemm(const float* __restrict__ X,
                                              const float* __restrict__ W,
                                              const float* __restrict__ al,
                                              const float* __restrict__ ar,
                                              u32* __restrict__ emb,
                                              float* __restrict__ sl, float* __restrict__ sr) {
  __shared__ unsigned char lds[49152];
  const int tid = threadIdx.x;
  const int n0 = blockIdx.x * 64;
  const int lane = tid & 63;
  const int w = tid >> 6;

  // stage W (f32 -> bf16), linear coalesced reads: 128x128 = 4096 float4s
#pragma unroll
  for (int i = 0; i < 16; ++i) {
    int idx = tid + i * 256;
    int n = idx >> 5, c4 = idx & 31;
    float4 v = ((const float4*)W)[idx];
    u32 p0 = (u32)f2b(v.x) | ((u32)f2b(v.y) << 16);
    u32 p1 = (u32)f2b(v.z) | ((u32)f2b(v.w) << 16);
    *(uint2*)&lds[WS_BASE + swz(n, c4 * 8)] = make_uint2(p0, p1);
  }
  // stage X tile (f32 -> bf16): 64x128 = 2048 float4s
#pragma unroll
  for (int i = 0; i < 8; ++i) {
    int idx = tid + i * 256;
    int r = idx >> 5, c4 = idx & 31;
    int n = n0 + r;
    float4 v = make_float4(0.f, 0.f, 0.f, 0.f);
    if (n < NN) v = ((const float4*)X)[n * 32 + c4];
    u32 p0 = (u32)f2b(v.x) | ((u32)f2b(v.y) << 16);
    u32 p1 = (u32)f2b(v.z) | ((u32)f2b(v.w) << 16);
    *(uint2*)&lds[XS_BASE + swz(r, c4 * 8)] = make_uint2(p0, p1);
  }
  __syncthreads();

  f32x4 acc[8];
#pragma unroll
  for (int nt = 0; nt < 8; ++nt) acc[nt] = (f32x4){0.f, 0.f, 0.f, 0.f};

  const int lr = w * 16 + (lane & 15);      // A row (local)
#pragma unroll
  for (int kk = 0; kk < 4; ++kk) {
    const int kb = kk * 64 + (lane >> 4) * 16;   // byte offset of this lane's 8 k-values
    short8 a = *(const short8*)&lds[XS_BASE + swz(lr, kb)];
#pragma unroll
    for (int nt = 0; nt < 8; ++nt) {
      int n = nt * 16 + (lane & 15);
      short8 b = *(const short8*)&lds[WS_BASE + swz(n, kb)];
      acc[nt] = __builtin_amdgcn_mfma_f32_16x16x32_bf16(a, b, acc[nt], 0, 0, 0);
    }
  }

  // fused scores: head = nt, channel-within-head = lane&15.
  // score_l[row][nt] = sum_{cwh} D[row][nt*16+cwh] * al[cwh*8+nt]
  {
    const int cwh = lane & 15;
    float av[8], bv[8];
#pragma unroll
    for (int h = 0; h < 8; ++h) { av[h] = al[cwh * 8 + h]; bv[h] = ar[cwh * 8 + h]; }
#pragma unroll
    for (int reg = 0; reg < 4; ++reg) {
      const int row = n0 + w * 16 + (lane >> 4) * 4 + reg;
#pragma unroll
      for (int nt = 0; nt < 8; ++nt) {
        float vl = acc[nt][reg] * av[nt];
        float vr = acc[nt][reg] * bv[nt];
        vl += __shfl_xor(vl, 1); vr += __shfl_xor(vr, 1);
        vl += __shfl_xor(vl, 2); vr += __shfl_xor(vr, 2);
        vl += __shfl_xor(vl, 4); vr += __shfl_xor(vr, 4);
        vl += __shfl_xor(vl, 8); vr += __shfl_xor(vr, 8);
        if (cwh == 0 && row < NN) {
          sl[row * HH + nt] = vl;
          sr[row * HH + nt] = vr;
        }
      }
    }
  }

  // stage accumulators to LDS (bf16) then coalesced global write
  __syncthreads();   // everyone done reading Xs
#pragma unroll
  for (int nt = 0; nt < 8; ++nt) {
    const int col = nt * 16 + (lane & 15);
#pragma unroll
    for (int reg = 0; reg < 4; ++reg) {
      const int r = w * 16 + (lane >> 4) * 4 + reg;
      *(u16*)&lds[XS_BASE + swz(r, col * 2)] = f2b(acc[nt][reg]);
    }
  }
  __syncthreads();
#pragma unroll
  for (int i = 0; i < 4; ++i) {
    int idx = tid + i * 256;        // 1024 uint4 chunks
    int r = idx >> 4, cb = (idx & 15) * 16;
    int n = n0 + r;
    if (n < NN) {
      uint4 v = *(const uint4*)&lds[XS_BASE + swz(r, cb)];
      *((uint4*)(emb + n * 64 + (idx & 15) * 4)) = v;
    }
  }
}

// ---- CSR build: histogram (direct from edge_index), scan, scatter ---------
__global__ __launch_bounds__(256) void k_hist(const int* __restrict__ ei, const int* __restrict__ flag,
                                              int* __restrict__ cnt) {
  int e = blockIdx.x * 256 + threadIdx.x;
  if (e >= EE) return;
  int t = flag[0] ? ei[EE + e] : ei[2 * EE + 2 * e];
  atomicAdd(&cnt[t], 1);
}

__global__ __launch_bounds__(256) void k_scanA(const int* __restrict__ cnt, int* __restrict__ offs,
                                               int* __restrict__ bsum) {
  __shared__ int tmp[256];
  const int t = threadIdx.x;
  const int i = blockIdx.x * 256 + t;
  int v = (i < NN) ? cnt[i] : 0;
  tmp[t] = v;
  __syncthreads();
#pragma unroll
  for (int d = 1; d < 256; d <<= 1) {
    int x = (t >= d) ? tmp[t - d] : 0;
    __syncthreads();
    tmp[t] += x;
    __syncthreads();
  }
  if (i < NN) offs[i] = tmp[t] - v;      // block-local exclusive
  if (t == 255) bsum[blockIdx.x] = tmp[255];
}

__global__ __launch_bounds__(256) void k_scanB(int* __restrict__ bsum, int nb) {
  __shared__ int tmp[256];
  const int t = threadIdx.x;
  int v = (t < nb) ? bsum[t] : 0;
  tmp[t] = v;
  __syncthreads();
#pragma unroll
  for (int d = 1; d < 256; d <<= 1) {
    int x = (t >= d) ? tmp[t - d] : 0;
    __syncthreads();
    tmp[t] += x;
    __syncthreads();
  }
  if (t < nb) bsum[t] = tmp[t] - v;      // exclusive
}

__global__ __launch_bounds__(256) void k_scanC(const int* __restrict__ bsum, int* __restrict__ offs,
                                               int* __restrict__ cur) {
  const int i = blockIdx.x * 256 + threadIdx.x;
  if (i < NN) {
    int o = offs[i] + bsum[blockIdx.x];
    offs[i] = o;
    cur[i] = o;
  }
  if (i == 0) offs[NN] = EE;
}

__global__ __launch_bounds__(256) void k_scatter(const int* __restrict__ ei, const int* __restrict__ flag,
                                                 int* __restrict__ cur, int* __restrict__ ssrc) {
  int e = blockIdx.x * 256 + threadIdx.x;
  if (e >= EE) return;
  int t, s;
  if (flag[0]) { s = ei[e]; t = ei[EE + e]; }
  else         { s = ei[2 * e]; t = ei[2 * EE + 2 * e]; }
  int pos = atomicAdd(&cur[t], 1);
  ssrc[pos] = s;
}

// ---- single-pass aggregation, 4-edge MLP unroll ---------------------------
__global__ __launch_bounds__(256) void k_agg(const u32* __restrict__ emb,
                                             const float* __restrict__ sl, const float* __restrict__ sr,
                                             const int* __restrict__ offs, const int* __restrict__ ssrc,
                                             const float* __restrict__ bias, float* __restrict__ out) {
  const int t = (blockIdx.x * 256 + threadIdx.x) >> 6;
  const int lane = threadIdx.x & 63;
  if (t >= NN) return;
  const int e0 = offs[t], e1 = offs[t + 1];
  const int h2 = lane >> 3;            // head owning channels (2*lane, 2*lane+1)
  const float sr2 = sr[t * HH + h2];
  float ax = 0.f, ay = 0.f, den = 0.f;
  int e = e0;
  for (; e + 4 <= e1; e += 4) {
    int s0 = ssrc[e + 0], s1 = ssrc[e + 1], s2 = ssrc[e + 2], s3 = ssrc[e + 3];
    float v0 = sl[s0 * HH + h2], v1 = sl[s1 * HH + h2];
    float v2 = sl[s2 * HH + h2], v3 = sl[s3 * HH + h2];
    u32 p0 = emb[s0 * 64 + lane], p1 = emb[s1 * 64 + lane];
    u32 p2 = emb[s2 * 64 + lane], p3 = emb[s3 * 64 + lane];
    v0 += sr2; v0 = (v0 > 0.f) ? v0 : 0.2f * v0; float w0 = __expf(v0);
    v1 += sr2; v1 = (v1 > 0.f) ? v1 : 0.2f * v1; float w1 = __expf(v1);
    v2 += sr2; v2 = (v2 > 0.f) ? v2 : 0.2f * v2; float w2 = __expf(v2);
    v3 += sr2; v3 = (v3 > 0.f) ? v3 : 0.2f * v3; float w3 = __expf(v3);
    den += w0 + w1 + w2 + w3;
    ax = fmaf(w0, b2f(p0 & 0xffffu), ax); ay = fmaf(w0, b2f(p0 >> 16), ay);
    ax = fmaf(w1, b2f(p1 & 0xffffu), ax); ay = fmaf(w1, b2f(p1 >> 16), ay);
    ax = fmaf(w2, b2f(p2 & 0xffffu), ax); ay = fmaf(w2, b2f(p2 >> 16), ay);
    ax = fmaf(w3, b2f(p3 & 0xffffu), ax); ay = fmaf(w3, b2f(p3 >> 16), ay);
  }
  for (; e < e1; ++e) {
    int s = ssrc[e];
    float v = sl[s * HH + h2] + sr2;
    v = (v > 0.f) ? v : 0.2f * v;
    float w = __expf(v);
    den += w;
    u32 p = emb[s * 64 + lane];
    ax = fmaf(w, b2f(p & 0xffffu), ax);
    ay = fmaf(w, b2f(p >> 16), ay);
  }
  const float inv = 1.f / (den + 1e-16f);
  float2 bv = ((const float2*)bias)[lane];
  ((float2*)out)[t * 64 + lane] = make_float2(fmaf(ax, inv, bv.x), fmaf(ay, inv, bv.y));
}

extern "C" void kernel_launch(void* const* d_in, const int* in_sizes, int n_in,
                              void* d_out, int out_size, void* d_ws, size_t ws_size,
                              hipStream_t stream) {
  const float* X  = (const float*)d_in[0];
  const int*   EI = (const int*)d_in[1];
  const float* W  = (const float*)d_in[2];
  const float* AL = (const float*)d_in[3];
  const float* AR = (const float*)d_in[4];
  const float* B  = (const float*)d_in[5];
  float* out = (float*)d_out;
  u32* ws = (u32*)d_ws;

  int*   flag = (int*)(ws + OFF_FLAG);
  int*   cnt  = (int*)(ws + OFF_CNT);
  int*   offs = (int*)(ws + OFF_OFFS);
  int*   cur  = (int*)(ws + OFF_CUR);
  int*   bsum = (int*)(ws + OFF_BSUM);
  float* sl   = (float*)(ws + OFF_SL);
  float* sr   = (float*)(ws + OFF_SR);
  int*   ssrc = (int*)(ws + OFF_SSRC);
  u32*   emb  = (u32*)(ws + OFF_EMB);

  const int nbN = (NN + 255) / 256;     // 196
  const int nbE = (EE + 255) / 256;     // 2344

  k_detect_zero<<<nbN, 256, 0, stream>>>(EI, flag, cnt);
  k_gemm<<<(NN + 63) / 64, 256, 0, stream>>>(X, W, AL, AR, emb, sl, sr);
  k_hist<<<nbE, 256, 0, stream>>>(EI, flag, cnt);
  k_scanA<<<nbN, 256, 0, stream>>>(cnt, offs, bsum);
  k_scanB<<<1, 256, 0, stream>>>(bsum, nbN);
  k_scanC<<<nbN, 256, 0, stream>>>(bsum, offs, cur);
  k_scatter<<<nbE, 256, 0, stream>>>(EI, flag, cur, ssrc);
  k_agg<<<(NN * 64 + 255) / 256, 256, 0, stream>>>(emb, sl, sr, offs, ssrc, B, out);
}